// Round 8
// baseline (283.407 us; speedup 1.0000x reference)
//
#include <hip/hip_runtime.h>

#define N_ 8192
#define D_ 256
#define KRANGE 2048
#define BM 128
#define BK 128
#define NSTEP (KRANGE / BK)   // 16

typedef short short8 __attribute__((ext_vector_type(8)));
typedef unsigned short u16x4 __attribute__((ext_vector_type(4)));
typedef unsigned short u16x8 __attribute__((ext_vector_type(8)));
typedef float f32x4 __attribute__((ext_vector_type(4)));

__device__ __forceinline__ unsigned short f2bf(float f) {
    union { float f; unsigned u; } v; v.f = f;
    unsigned r = v.u + 0x7FFFu + ((v.u >> 16) & 1u);
    return (unsigned short)(r >> 16);
}
__device__ __forceinline__ float bf2f(unsigned short h) {
    union { unsigned u; float f; } v; v.u = ((unsigned)h) << 16;
    return v.f;
}

// ---------------- K1: disK[r] = rsqrt(rowsum(A_r) + 2) ----------------------
__global__ __launch_bounds__(256) void k_dis(const float* __restrict__ A,
                                             float* __restrict__ disK) {
    const int w = threadIdx.x >> 6, l = threadIdx.x & 63;
    const int row = blockIdx.x * 4 + w;
    const float4* Ar = (const float4*)(A + (size_t)row * N_);
    float s = 0.f;
    #pragma unroll 8
    for (int i = l; i < N_ / 4; i += 64) {
        float4 v = Ar[i];
        s += (v.x + v.y) + (v.z + v.w);
    }
    #pragma unroll
    for (int o = 32; o; o >>= 1) s += __shfl_down(s, o);
    if (l == 0) disK[row] = rsqrtf(s + 2.0f);
}

// ---------------- K2: P = X@W^T ; Corr = 2*dis^2*P + b ; Zt = (dis*P)^T -----
__global__ __launch_bounds__(256) void k_P(
    const float* __restrict__ X, const float* __restrict__ W,
    const float* __restrict__ bv, const float* __restrict__ disK,
    unsigned short* __restrict__ Corr, unsigned short* __restrict__ Zt)
{
    __shared__ float sX[8][256];
    const int t = threadIdx.x;
    const int i0 = blockIdx.x * 8;

    {
        const int xr = t >> 5, xc = (t & 31) * 8;
        const float* src = X + (size_t)(i0 + xr) * D_ + xc;
        *(float4*)&sX[xr][xc]     = *(const float4*)(src);
        *(float4*)&sX[xr][xc + 4] = *(const float4*)(src + 4);
    }
    __syncthreads();

    const int c = t;
    float acc8[8];
    #pragma unroll
    for (int rr = 0; rr < 8; ++rr) acc8[rr] = 0.f;
    const float4* Wr = (const float4*)(W + (size_t)c * D_);
    for (int k4 = 0; k4 < 64; ++k4) {
        const float4 wv = Wr[k4];
        #pragma unroll
        for (int rr = 0; rr < 8; ++rr) {
            const float4 xv = *(const float4*)&sX[rr][k4 * 4];
            acc8[rr] += xv.x * wv.x + xv.y * wv.y + xv.z * wv.z + xv.w * wv.w;
        }
    }
    const float bc = bv[c];
    u16x8 zcol;
    #pragma unroll
    for (int rr = 0; rr < 8; ++rr) {
        const float p = acc8[rr];
        const float dv = disK[i0 + rr];
        Corr[(size_t)(i0 + rr) * D_ + c] = f2bf(2.0f * dv * dv * p + bc);
        zcol[rr] = f2bf(dv * p);
    }
    *(u16x8*)(Zt + (size_t)c * N_ + i0) = zcol;
}

#define KBAR() do {                                             \
    asm volatile("s_waitcnt lgkmcnt(0)" ::: "memory");          \
    __builtin_amdgcn_sched_barrier(0);                          \
    __builtin_amdgcn_s_barrier();                               \
    __builtin_amdgcn_sched_barrier(0);                          \
} while (0)

// ---------------- K3: Cpart[ks] = A[:, kslice] @ Z[kslice, :] ---------------
// BK=128: per-row A-chunk = 512 B (HBM page-friendly), 16 steps, 64 MFMA/wave
// per barrier. Grid 256 = 64 M-tiles x 4 K-slices (K-slice pinned per XCD
// pair). Dbuf LDS-A 68 KB; B global->reg from L2-resident Zt slice.
__global__ __launch_bounds__(512) void kB(
    const float* __restrict__ A, const unsigned short* __restrict__ Zt,
    float* __restrict__ Cpart)
{
    __shared__ unsigned short sA[2][BM][BK + 8];   // 68 KB, 2-way read conflicts

    const int t = threadIdx.x, lane = t & 63, wid = t >> 6;
    const int d = (int)blockIdx.x;
    const int ks = (d & 7) >> 1;                    // K-slice 0..3
    const int mx = ((d >> 3) << 1) | (d & 1);       // M-tile 0..63
    const int m0 = mx * BM;
    const int kb = ks * KRANGE;
    const int bn = wid * 32;

    const int sr = t >> 2, sq = t & 3;              // stage: row, 32-f32 span
    const float* Ast = A + (size_t)(m0 + sr) * N_ + kb + sq * 32;
    const unsigned short* Bq0 = Zt + (size_t)(bn + (lane & 15)) * N_ + kb + (lane >> 4) * 8;
    const unsigned short* Bq1 = Bq0 + (size_t)16 * N_;

    f32x4 acc[8][2];
    #pragma unroll
    for (int m = 0; m < 8; ++m)
        #pragma unroll
        for (int n = 0; n < 2; ++n) acc[m][n] = (f32x4){0.f, 0.f, 0.f, 0.f};

    f32x4 s0[8], s1[8];
    short8 bqA[2][4], bqB[2][4];

    auto ldA = [&](f32x4 (&s)[8], int ts) {
        const f32x4* p = (const f32x4*)(Ast + (size_t)min(ts, NSTEP - 1) * BK);
        #pragma unroll
        for (int j = 0; j < 8; ++j) s[j] = __builtin_nontemporal_load(p + j);
    };
    auto stage = [&](int buf, const f32x4 (&s)[8]) {
        #pragma unroll
        for (int j = 0; j < 8; ++j) {
            u16x4 h; h[0]=f2bf(s[j][0]); h[1]=f2bf(s[j][1]);
                     h[2]=f2bf(s[j][2]); h[3]=f2bf(s[j][3]);
            *(u16x4*)&sA[buf][sr][sq * 32 + j * 4] = h;
        }
    };
    auto loadB = [&](int ts, short8 (&bq)[2][4]) {
        const int k0 = min(ts, NSTEP - 1) * BK;
        #pragma unroll
        for (int kk = 0; kk < 4; ++kk) {
            bq[0][kk] = *(const short8*)(Bq0 + k0 + kk * 32);
            bq[1][kk] = *(const short8*)(Bq1 + k0 + kk * 32);
        }
    };
    auto comp = [&](int buf, const short8 (&bq)[2][4]) {
        #pragma unroll
        for (int mf = 0; mf < 8; ++mf) {
            short8 af[4];
            #pragma unroll
            for (int kk = 0; kk < 4; ++kk)
                af[kk] = *(const short8*)&sA[buf][mf * 16 + (lane & 15)]
                                             [kk * 32 + (lane >> 4) * 8];
            #pragma unroll
            for (int kk = 0; kk < 4; ++kk)
                #pragma unroll
                for (int nf = 0; nf < 2; ++nf)
                    acc[mf][nf] = __builtin_amdgcn_mfma_f32_16x16x32_bf16(
                        af[kk], bq[nf][kk], acc[mf][nf], 0, 0, 0);
        }
    };

    // prologue: tiles 0,1 in regs; B(0); stage tile0 -> buf0
    ldA(s0, 0); ldA(s1, 1);
    loadB(0, bqA);
    stage(0, s0);
    KBAR();

    for (int it = 0; it < NSTEP / 2; ++it) {
        const int ts = it * 2;
        // even step ts: compute buf0/bqA
        stage(1, s1);
        ldA(s0, ts + 2);
        loadB(ts + 1, bqB);
        comp(0, bqA);
        KBAR();
        // odd step ts+1: compute buf1/bqB
        stage(0, s0);
        ldA(s1, ts + 3);
        loadB(ts + 2, bqA);
        comp(1, bqB);
        KBAR();
    }

    // epilogue: raw partials -> Cpart[ks]
    float* Cp = Cpart + (size_t)ks * ((size_t)N_ * D_);
    #pragma unroll
    for (int mf = 0; mf < 8; ++mf)
        #pragma unroll
        for (int r = 0; r < 4; ++r) {
            const int i = m0 + mf * 16 + ((lane >> 4) << 2) + r;
            #pragma unroll
            for (int nf = 0; nf < 2; ++nf) {
                const int c = bn + nf * 16 + (lane & 15);
                Cp[(size_t)i * D_ + c] = acc[mf][nf][r];
            }
        }
}

// ---------------- K4: out = relu(dis_i * sum_ks Cpart + Corr) ---------------
__global__ __launch_bounds__(256) void k_fin(
    const float* __restrict__ Cpart, const float* __restrict__ disK,
    const unsigned short* __restrict__ Corr, float* __restrict__ out)
{
    const size_t PL = (size_t)N_ * D_;
    const int tid = blockIdx.x * 256 + threadIdx.x;
    const size_t base = (size_t)tid * 4;
    const int i = (int)(base >> 8);
    const f32x4 p0 = *(const f32x4*)(Cpart + base);
    const f32x4 p1 = *(const f32x4*)(Cpart + PL + base);
    const f32x4 p2 = *(const f32x4*)(Cpart + 2 * PL + base);
    const f32x4 p3 = *(const f32x4*)(Cpart + 3 * PL + base);
    const u16x4 cr = *(const u16x4*)(Corr + base);
    const float dv = disK[i];
    f32x4 o;
    #pragma unroll
    for (int j = 0; j < 4; ++j)
        o[j] = fmaxf(dv * ((p0[j] + p1[j]) + (p2[j] + p3[j])) + bf2f(cr[j]), 0.f);
    *(f32x4*)(out + base) = o;
}

extern "C" void kernel_launch(void* const* d_in, const int* in_sizes, int n_in,
                              void* d_out, int out_size, void* d_ws, size_t ws_size,
                              hipStream_t stream) {
    (void)in_sizes; (void)n_in; (void)out_size; (void)ws_size;
    const float* X = (const float*)d_in[0];
    const float* A = (const float*)d_in[1];
    const float* W = (const float*)d_in[2];
    const float* b = (const float*)d_in[3];
    float* outp = (float*)d_out;

    float* disK = (float*)d_ws;                                          // 32 KB
    unsigned short* Corr = (unsigned short*)((char*)d_ws + 32768);       // 4 MB
    unsigned short* Zt   = Corr + (size_t)N_ * D_;                       // 4 MB
    float* Cpart = (float*)((char*)d_ws + 32768 + 4 * (size_t)N_ * D_);  // 32 MB

    k_dis<<<N_ / 4, 256, 0, stream>>>(A, disK);
    k_P<<<N_ / 8, 256, 0, stream>>>(X, W, b, disK, Corr, Zt);
    kB<<<256, 512, 0, stream>>>(A, Zt, Cpart);
    k_fin<<<(N_ * D_) / 1024, 256, 0, stream>>>(Cpart, disK, Corr, outp);
}

// Round 9
// 172.659 us; speedup vs baseline: 1.6414x; 1.6414x over previous
//
#include <hip/hip_runtime.h>

#define N_ 8192
#define D_ 256
#define KRANGE 2048
#define BM 64
#define BK 64
#define NSTEP (KRANGE / BK)   // 32

typedef short short8 __attribute__((ext_vector_type(8)));
typedef unsigned short u16x4 __attribute__((ext_vector_type(4)));
typedef unsigned short u16x8 __attribute__((ext_vector_type(8)));
typedef float f32x4 __attribute__((ext_vector_type(4)));

__device__ __forceinline__ unsigned short f2bf(float f) {
    union { float f; unsigned u; } v; v.f = f;
    unsigned r = v.u + 0x7FFFu + ((v.u >> 16) & 1u);
    return (unsigned short)(r >> 16);
}
__device__ __forceinline__ float bf2f(unsigned short h) {
    union { unsigned u; float f; } v; v.u = ((unsigned)h) << 16;
    return v.f;
}

// ---------------- K1: disK[r] = rsqrt(rowsum(A_r) + 2) ----------------------
__global__ __launch_bounds__(256) void k_dis(const float* __restrict__ A,
                                             float* __restrict__ disK) {
    const int w = threadIdx.x >> 6, l = threadIdx.x & 63;
    const int row = blockIdx.x * 4 + w;
    const float4* Ar = (const float4*)(A + (size_t)row * N_);
    float s = 0.f;
    #pragma unroll 8
    for (int i = l; i < N_ / 4; i += 64) {
        float4 v = Ar[i];
        s += (v.x + v.y) + (v.z + v.w);
    }
    #pragma unroll
    for (int o = 32; o; o >>= 1) s += __shfl_down(s, o);
    if (l == 0) disK[row] = rsqrtf(s + 2.0f);
}

// ---------------- K2: P = X@W^T ; Corr = 2*dis^2*P + b ; Zt = (dis*P)^T -----
__global__ __launch_bounds__(256) void k_P(
    const float* __restrict__ X, const float* __restrict__ W,
    const float* __restrict__ bv, const float* __restrict__ disK,
    unsigned short* __restrict__ Corr, unsigned short* __restrict__ Zt)
{
    __shared__ float sX[8][256];
    const int t = threadIdx.x;
    const int i0 = blockIdx.x * 8;

    {
        const int xr = t >> 5, xc = (t & 31) * 8;
        const float* src = X + (size_t)(i0 + xr) * D_ + xc;
        *(float4*)&sX[xr][xc]     = *(const float4*)(src);
        *(float4*)&sX[xr][xc + 4] = *(const float4*)(src + 4);
    }
    __syncthreads();

    const int c = t;
    float acc8[8];
    #pragma unroll
    for (int rr = 0; rr < 8; ++rr) acc8[rr] = 0.f;
    const float4* Wr = (const float4*)(W + (size_t)c * D_);
    for (int k4 = 0; k4 < 64; ++k4) {
        const float4 wv = Wr[k4];
        #pragma unroll
        for (int rr = 0; rr < 8; ++rr) {
            const float4 xv = *(const float4*)&sX[rr][k4 * 4];
            acc8[rr] += xv.x * wv.x + xv.y * wv.y + xv.z * wv.z + xv.w * wv.w;
        }
    }
    const float bc = bv[c];
    u16x8 zcol;
    #pragma unroll
    for (int rr = 0; rr < 8; ++rr) {
        const float p = acc8[rr];
        const float dv = disK[i0 + rr];
        Corr[(size_t)(i0 + rr) * D_ + c] = f2bf(2.0f * dv * dv * p + bc);
        zcol[rr] = f2bf(dv * p);
    }
    *(u16x8*)(Zt + (size_t)c * N_ + i0) = zcol;
}

#define KBAR() do {                                             \
    asm volatile("s_waitcnt lgkmcnt(0)" ::: "memory");          \
    __builtin_amdgcn_sched_barrier(0);                          \
    __builtin_amdgcn_s_barrier();                               \
    __builtin_amdgcn_sched_barrier(0);                          \
} while (0)

// ---------------- K3: Cpart[ks] = A[:, kslice] @ Z[kslice, :] ---------------
// 2 blocks/CU (BM=64, 18.6 KB LDS, VGPR<=128): two independent barrier
// domains per CU keep the memory pipe fed through each other's vmcnt drains.
// K-slice pinned per XCD pair (B-slice 1 MB, L2-hot). Reverse-M: harvest the
// A-tail k_dis left in L3. Pad=4 u16 -> 2-way LDS read conflicts (free).
__global__ __launch_bounds__(512, 4) void kB(
    const float* __restrict__ A, const unsigned short* __restrict__ Zt,
    float* __restrict__ Cpart)
{
    __shared__ unsigned short sA[2][BM][BK + 4];   // 18.6 KB

    const int t = threadIdx.x, lane = t & 63, wid = t >> 6;
    const int d = (int)blockIdx.x;
    const int ks = (d & 7) >> 1;                    // K-slice 0..3 (2 XCDs each)
    const int mx = ((d >> 3) << 1) | (d & 1);       // M-tile 0..127
    const int m0 = (127 - mx) * BM;                 // reverse: L3 carry from k_dis
    const int kb = ks * KRANGE;
    const int bn = wid * 32;

    const int sr = t >> 3, sq = t & 7;              // stage: row, 8-f32 span
    const float* Ast = A + (size_t)(m0 + sr) * N_ + kb + sq * 8;
    const unsigned short* Bq0 = Zt + (size_t)(bn + (lane & 15)) * N_ + kb + (lane >> 4) * 8;
    const unsigned short* Bq1 = Bq0 + (size_t)16 * N_;

    f32x4 acc[4][2];
    #pragma unroll
    for (int m = 0; m < 4; ++m)
        #pragma unroll
        for (int n = 0; n < 2; ++n) acc[m][n] = (f32x4){0.f, 0.f, 0.f, 0.f};

    f32x4 s0[2], s1[2];
    short8 bqA[2][2], bqB[2][2];

    auto ldA = [&](f32x4 (&s)[2], int ts) {
        const f32x4* p = (const f32x4*)(Ast + (size_t)min(ts, NSTEP - 1) * BK);
        s[0] = p[0]; s[1] = p[1];
    };
    auto stage = [&](int buf, const f32x4 (&s)[2]) {
        #pragma unroll
        for (int j = 0; j < 2; ++j) {
            u16x4 h; h[0]=f2bf(s[j][0]); h[1]=f2bf(s[j][1]);
                     h[2]=f2bf(s[j][2]); h[3]=f2bf(s[j][3]);
            *(u16x4*)&sA[buf][sr][sq * 8 + j * 4] = h;
        }
    };
    auto loadB = [&](int ts, short8 (&bq)[2][2]) {
        const int k0 = min(ts, NSTEP - 1) * BK;
        #pragma unroll
        for (int kk = 0; kk < 2; ++kk) {
            bq[0][kk] = *(const short8*)(Bq0 + k0 + kk * 32);
            bq[1][kk] = *(const short8*)(Bq1 + k0 + kk * 32);
        }
    };
    auto comp = [&](int buf, const short8 (&bq)[2][2]) {
        #pragma unroll
        for (int mf = 0; mf < 4; ++mf) {
            short8 af[2];
            #pragma unroll
            for (int kk = 0; kk < 2; ++kk)
                af[kk] = *(const short8*)&sA[buf][mf * 16 + (lane & 15)]
                                             [kk * 32 + (lane >> 4) * 8];
            #pragma unroll
            for (int kk = 0; kk < 2; ++kk)
                #pragma unroll
                for (int nf = 0; nf < 2; ++nf)
                    acc[mf][nf] = __builtin_amdgcn_mfma_f32_16x16x32_bf16(
                        af[kk], bq[nf][kk], acc[mf][nf], 0, 0, 0);
        }
    };

    // prologue: tiles 0,1 in regs; B(0); stage tile0 -> buf0
    ldA(s0, 0); ldA(s1, 1);
    loadB(0, bqA);
    stage(0, s0);
    KBAR();

    for (int it = 0; it < NSTEP / 2; ++it) {
        const int ts = it * 2;
        // even step: compute buf0/bqA
        stage(1, s1);
        ldA(s0, ts + 2);
        loadB(ts + 1, bqB);
        comp(0, bqA);
        KBAR();
        // odd step: compute buf1/bqB
        stage(0, s0);
        ldA(s1, ts + 3);
        loadB(ts + 2, bqA);
        comp(1, bqB);
        KBAR();
    }

    // epilogue: raw partials -> Cpart[ks]
    float* Cp = Cpart + (size_t)ks * ((size_t)N_ * D_);
    #pragma unroll
    for (int mf = 0; mf < 4; ++mf)
        #pragma unroll
        for (int r = 0; r < 4; ++r) {
            const int i = m0 + mf * 16 + ((lane >> 4) << 2) + r;
            #pragma unroll
            for (int nf = 0; nf < 2; ++nf) {
                const int c = bn + nf * 16 + (lane & 15);
                Cp[(size_t)i * D_ + c] = acc[mf][nf][r];
            }
        }
}

// ---------------- K4: out = relu(dis_i * sum_ks Cpart + Corr) ---------------
__global__ __launch_bounds__(256) void k_fin(
    const float* __restrict__ Cpart, const float* __restrict__ disK,
    const unsigned short* __restrict__ Corr, float* __restrict__ out)
{
    const size_t PL = (size_t)N_ * D_;
    const int tid = blockIdx.x * 256 + threadIdx.x;
    const size_t base = (size_t)tid * 4;
    const int i = (int)(base >> 8);
    const f32x4 p0 = *(const f32x4*)(Cpart + base);
    const f32x4 p1 = *(const f32x4*)(Cpart + PL + base);
    const f32x4 p2 = *(const f32x4*)(Cpart + 2 * PL + base);
    const f32x4 p3 = *(const f32x4*)(Cpart + 3 * PL + base);
    const u16x4 cr = *(const u16x4*)(Corr + base);
    const float dv = disK[i];
    f32x4 o;
    #pragma unroll
    for (int j = 0; j < 4; ++j)
        o[j] = fmaxf(dv * ((p0[j] + p1[j]) + (p2[j] + p3[j])) + bf2f(cr[j]), 0.f);
    *(f32x4*)(out + base) = o;
}

extern "C" void kernel_launch(void* const* d_in, const int* in_sizes, int n_in,
                              void* d_out, int out_size, void* d_ws, size_t ws_size,
                              hipStream_t stream) {
    (void)in_sizes; (void)n_in; (void)out_size; (void)ws_size;
    const float* X = (const float*)d_in[0];
    const float* A = (const float*)d_in[1];
    const float* W = (const float*)d_in[2];
    const float* b = (const float*)d_in[3];
    float* outp = (float*)d_out;

    float* disK = (float*)d_ws;                                          // 32 KB
    unsigned short* Corr = (unsigned short*)((char*)d_ws + 32768);       // 4 MB
    unsigned short* Zt   = Corr + (size_t)N_ * D_;                       // 4 MB
    float* Cpart = (float*)((char*)d_ws + 32768 + 4 * (size_t)N_ * D_);  // 32 MB

    k_dis<<<N_ / 4, 256, 0, stream>>>(A, disK);
    k_P<<<N_ / 8, 256, 0, stream>>>(X, W, b, disK, Corr, Zt);
    kB<<<512, 512, 0, stream>>>(A, Zt, Cpart);
    k_fin<<<(N_ * D_) / 1024, 256, 0, stream>>>(Cpart, disK, Corr, outp);
}